// Round 18
// baseline (184.282 us; speedup 1.0000x reference)
//
#include <hip/hip_runtime.h>
#include <float.h>

#define DD 52
#define VE 151
#define NTOT 393216
#define PSZ 131072

// output offsets (floats)
#define OFF0 0                       // predicate_conf  P*52
#define OFF1 (PSZ*DD)                // entity_conf     P*151
#define OFF2 (OFF1 + PSZ*VE)         // predicate_logits P*52
#define OFF3 (OFF2 + PSZ*DD)         // entity_logits   P*151
#define OFF4 (OFF3 + PSZ*VE)         // all_labels      N (as float)

#define SORT_BLOCKS 384              // N / 1024
#define TMR 32                       // rows per tile

typedef float f32x4 __attribute__((ext_vector_type(4)));

// ---------- count (blocks 0..383) + weight-fold (blocks 384..426) ----------
__global__ __launch_bounds__(256) void count_combine_kernel(const int* __restrict__ nt,
                                                            int* __restrict__ partial,
                                                            const float* __restrict__ FCw,
                                                            const float* __restrict__ FCb,
                                                            const float* __restrict__ Wpl,
                                                            const float* __restrict__ Went,
                                                            float* __restrict__ Wc,
                                                            float* __restrict__ bc,
                                                            float* __restrict__ Wpc,
                                                            float* __restrict__ bpc) {
  int tid = threadIdx.x;
  if (blockIdx.x < SORT_BLOCKS) {
    __shared__ int cnt[3];
    if (tid < 3) cnt[tid] = 0;
    __syncthreads();
    int base = blockIdx.x * 1024 + tid * 4;
    int4 v = *(const int4*)(nt + base);
    int t0 = min(max(v.x, 0), 2), t1 = min(max(v.y, 0), 2);
    int t2 = min(max(v.z, 0), 2), t3 = min(max(v.w, 0), 2);
    atomicAdd(&cnt[t0], 1); atomicAdd(&cnt[t1], 1);
    atomicAdd(&cnt[t2], 1); atomicAdd(&cnt[t3], 1);
    __syncthreads();
    if (tid < 3) partial[blockIdx.x * 3 + tid] = cnt[tid];
  } else {
    int idx = (blockIdx.x - SORT_BLOCKS) * 256 + tid;
    if (idx < VE * DD) {
      int v = idx / DD, k = idx % DD;
      float s = 0.f;
      for (int d = 0; d < DD; ++d) s = fmaf(Went[v * DD + d], FCw[d * DD + k], s);
      Wc[idx] = s;
    } else if (idx < VE * DD + VE) {
      int v = idx - VE * DD;
      float s = 0.f;
      for (int d = 0; d < DD; ++d) s = fmaf(FCb[d], Went[v * DD + d], s);
      bc[v] = s;
    } else if (idx < VE * DD + VE + DD * DD) {
      int t2 = idx - (VE * DD + VE);
      int j = t2 / DD, k = t2 % DD;
      float s = 0.f;
      for (int d = 0; d < DD; ++d) s = fmaf(FCw[d * DD + k], Wpl[d * DD + j], s);
      Wpc[t2] = s;
    } else if (idx < VE * DD + VE + DD * DD + DD) {
      int j = idx - (VE * DD + VE + DD * DD);
      float s = 0.f;
      for (int d = 0; d < DD; ++d) s = fmaf(FCb[d], Wpl[d * DD + j], s);
      bpc[j] = s;
    }
  }
}

__global__ __launch_bounds__(384) void scan_kernel(const int* __restrict__ partial,
                                                   int* __restrict__ blockBase) {
  __shared__ int sA[3][SORT_BLOCKS];
  int b = threadIdx.x;
  int p0 = partial[b * 3 + 0], p1 = partial[b * 3 + 1], p2 = partial[b * 3 + 2];
  sA[0][b] = p0; sA[1][b] = p1; sA[2][b] = p2;
  __syncthreads();
  for (int off = 1; off < SORT_BLOCKS; off <<= 1) {
    int a0 = 0, a1 = 0, a2 = 0;
    if (b >= off) { a0 = sA[0][b - off]; a1 = sA[1][b - off]; a2 = sA[2][b - off]; }
    __syncthreads();
    sA[0][b] += a0; sA[1][b] += a1; sA[2][b] += a2;
    __syncthreads();
  }
  int tot0 = sA[0][SORT_BLOCKS - 1];
  int tot1 = sA[1][SORT_BLOCKS - 1];
  blockBase[b * 3 + 0] = sA[0][b] - p0;
  blockBase[b * 3 + 1] = tot0 + sA[1][b] - p1;
  blockBase[b * 3 + 2] = tot0 + tot1 + sA[2][b] - p2;
}

__global__ __launch_bounds__(256) void scatter_kernel(const int* __restrict__ nt,
                                                      const int* __restrict__ blockBase,
                                                      int* __restrict__ order) {
  __shared__ int s0[256], s1[256], s2[256];
  int tid = threadIdx.x;
  int gbase = blockIdx.x * 1024 + tid * 4;
  int4 v = *(const int4*)(nt + gbase);
  int t[4] = { min(max(v.x, 0), 2), min(max(v.y, 0), 2),
               min(max(v.z, 0), 2), min(max(v.w, 0), 2) };
  int c0 = 0, c1 = 0, c2 = 0;
#pragma unroll
  for (int i = 0; i < 4; ++i) { c0 += (t[i] == 0); c1 += (t[i] == 1); c2 += (t[i] == 2); }
  s0[tid] = c0; s1[tid] = c1; s2[tid] = c2;
  __syncthreads();
  for (int off = 1; off < 256; off <<= 1) {
    int a0 = 0, a1 = 0, a2 = 0;
    if (tid >= off) { a0 = s0[tid - off]; a1 = s1[tid - off]; a2 = s2[tid - off]; }
    __syncthreads();
    s0[tid] += a0; s1[tid] += a1; s2[tid] += a2;
    __syncthreads();
  }
  int o0 = blockBase[blockIdx.x * 3 + 0] + s0[tid] - c0;
  int o1 = blockBase[blockIdx.x * 3 + 1] + s1[tid] - c1;
  int o2 = blockBase[blockIdx.x * 3 + 2] + s2[tid] - c2;
#pragma unroll
  for (int i = 0; i < 4; ++i) {
    int ty = t[i]; int dest;
    if (ty == 0) dest = o0++;
    else if (ty == 1) dest = o1++;
    else dest = o2++;
    order[dest] = gbase + i;
  }
}

// ---------- fused main kernel ----------
// Base = R17. R18 single variable: sOrd LDS staging REMOVED — gather and
// label-write read order[] directly (gather: 13 lanes broadcast one L1-hot
// dword; label-write: 8 scattered dword loads/tile). Removes 2 of 11
// barriers per ent tile. This also isolates the R7/R8 mystery: sOrd
// removal was bundled in that regression but cannot by mechanism cause
// store amplification — gate on WRITE to confirm or convict.
// INVARIANTS (session-measured, do not violate):
//  - h staged via LDS (R10: direct-global = latency-bound, +75%)
//  - epilogue: both surfaces staged in LDS, clean f32x4 NT store/thread/iter
//    (R5-R8: any deviation -> 4-16x HBM write amplification)
//  - 32-row tiles, acc[4][5] (R13/R14: acc[8][5] -> scratch, 3-10x)
__global__ __launch_bounds__(256, 3) void main_kernel(const float* __restrict__ h,
                                                      const int* __restrict__ order,
                                                      const float* __restrict__ Wc,
                                                      const float* __restrict__ bc,
                                                      const float* __restrict__ Wpc,
                                                      const float* __restrict__ bpc,
                                                      float* __restrict__ out) {
  __shared__ float sW[VE * DD];   // 31408 B (pred uses 52*52)
  __shared__ float sU[2416];      // 9664 B: h-tile (416 f4) / chunk buf (604 f4)
  __shared__ float sb[VE + 1];
  int tid = threadIdx.x, bid = blockIdx.x;
  int rg = tid >> 5, c0 = tid & 31;

  if (bid < 512) {
    // ---------- entity / blank ----------
    for (int i = tid; i < VE * 13; i += 256) ((float4*)sW)[i] = ((const float4*)Wc)[i];
    if (tid < VE) sb[tid] = bc[tid];
    int e = bid;

    int wbase[5];
#pragma unroll
    for (int j = 0; j < 5; ++j) {
      int col = c0 + 32 * j; if (col >= VE) col = 0;
      wbase[j] = col * 13;
    }
    int hbase[4];
#pragma unroll
    for (int r = 0; r < 4; ++r) hbase[r] = (rg + 8 * r) * 13;

#pragma unroll 1
    for (int tt = 0; tt < 16; ++tt) {
      bool isEnt = !(tt & 1);
      int idx = tt >> 1;
      int rowBase = (isEnt ? PSZ : 2 * PSZ) + e * 256 + idx * 32;

      __syncthreads();     // sU free (prev epilogue/compute reads done)
      for (int i = tid; i < TMR * 13; i += 256) {
        int row = i / 13, f = i % 13;
        int o = order[rowBase + row];
        ((float4*)sU)[i] = ((const float4*)(h + (size_t)o * DD))[f];
      }
      __syncthreads();

      float acc[4][5];
#pragma unroll
      for (int r = 0; r < 4; ++r)
#pragma unroll
        for (int j = 0; j < 5; ++j) acc[r][j] = 0.f;

#pragma unroll
      for (int kc = 0; kc < 13; ++kc) {
        float4 wv[5];
#pragma unroll
        for (int j = 0; j < 5; ++j)
          wv[j] = ((const float4*)sW)[wbase[j] + kc];
#pragma unroll
        for (int r = 0; r < 4; ++r) {
          float4 hv = ((float4*)sU)[hbase[r] + kc];
#pragma unroll
          for (int j = 0; j < 5; ++j) {
            acc[r][j] = fmaf(hv.x, wv[j].x, acc[r][j]);
            acc[r][j] = fmaf(hv.y, wv[j].y, acc[r][j]);
            acc[r][j] = fmaf(hv.z, wv[j].z, acc[r][j]);
            acc[r][j] = fmaf(hv.w, wv[j].w, acc[r][j]);
          }
        }
      }

      float bvpl[4];
#pragma unroll 1
      for (int r = 0; r < 4; ++r) {
        float bv = -FLT_MAX; int bi = 0x7fffffff;
#pragma unroll
        for (int j = 0; j < 5; ++j) {
          int col = c0 + 32 * j;
          if (col < VE) {
            float x = acc[r][j] + sb[col];
            acc[r][j] = x;
            if (x > bv) { bv = x; bi = col; }
          }
        }
#pragma unroll
        for (int m = 16; m >= 1; m >>= 1) {
          float ov = __shfl_xor(bv, m);
          int   oi = __shfl_xor(bi, m);
          if (ov > bv || (ov == bv && oi < bi)) { bv = ov; bi = oi; }
        }
        if (isEnt) {
          float s = 0.f;
#pragma unroll
          for (int j = 0; j < 5; ++j) {
            int col = c0 + 32 * j;
            if (col < VE) s += __expf(acc[r][j] - bv);
          }
#pragma unroll
          for (int m = 16; m >= 1; m >>= 1) s += __shfl_xor(s, m);
          bvpl[r] = bv + __logf(s);
        }
        if (c0 == 0) out[OFF4 + order[rowBase + rg + 8 * r]] = (float)bi;
      }

      if (isEnt) {
        int q0base = rowBase - PSZ;
#pragma unroll 1
        for (int c = 0; c < 4; ++c) {
          __syncthreads();
#pragma unroll
          for (int j = 0; j < 5; ++j) {
            int col = c0 + 32 * j;
            if (col < VE) {
              float lg = acc[c][j];
              sU[rg * VE + col] = lg - bvpl[c];
              sU[1208 + rg * VE + col] = lg;
            }
          }
          __syncthreads();
          int q0 = q0base + 8 * c;
          f32x4* dC = (f32x4*)(out + OFF1 + (size_t)q0 * VE);
          f32x4* dL = (f32x4*)(out + OFF3 + (size_t)q0 * VE);
          for (int i = tid; i < 604; i += 256) {
            f32x4 v = ((f32x4*)sU)[i];
            if (i < 302) __builtin_nontemporal_store(v, dC + i);
            else         __builtin_nontemporal_store(v, dL + (i - 302));
          }
        }
      }
    }
  } else {
    // ---------- predicate : 256 blocks x 16 tiles ----------
    for (int i = tid; i < DD * 13; i += 256) ((float4*)sW)[i] = ((const float4*)Wpc)[i];
    if (tid < DD) sb[tid] = bpc[tid];
    int p = bid - 512;

    int wbase[2];
#pragma unroll
    for (int j = 0; j < 2; ++j) {
      int col = c0 + 32 * j; if (col >= DD) col = 0;
      wbase[j] = col * 13;
    }
    int hbase[4];
#pragma unroll
    for (int r = 0; r < 4; ++r) hbase[r] = (rg + 8 * r) * 13;

#pragma unroll 1
    for (int tt = 0; tt < 16; ++tt) {
      int rowBase = p * 512 + tt * 32;

      __syncthreads();
      for (int i = tid; i < TMR * 13; i += 256) {
        int row = i / 13, f = i % 13;
        int o = order[rowBase + row];
        ((float4*)sU)[i] = ((const float4*)(h + (size_t)o * DD))[f];
      }
      __syncthreads();

      float acc[4][2];
#pragma unroll
      for (int r = 0; r < 4; ++r) { acc[r][0] = 0.f; acc[r][1] = 0.f; }

#pragma unroll
      for (int kc = 0; kc < 13; ++kc) {
        float4 wv[2];
#pragma unroll
        for (int j = 0; j < 2; ++j)
          wv[j] = ((const float4*)sW)[wbase[j] + kc];
#pragma unroll
        for (int r = 0; r < 4; ++r) {
          float4 hv = ((float4*)sU)[hbase[r] + kc];
#pragma unroll
          for (int j = 0; j < 2; ++j) {
            acc[r][j] = fmaf(hv.x, wv[j].x, acc[r][j]);
            acc[r][j] = fmaf(hv.y, wv[j].y, acc[r][j]);
            acc[r][j] = fmaf(hv.z, wv[j].z, acc[r][j]);
            acc[r][j] = fmaf(hv.w, wv[j].w, acc[r][j]);
          }
        }
      }

      float bvpl[4];
#pragma unroll 1
      for (int r = 0; r < 4; ++r) {
        float bv = -FLT_MAX; int bi = 0x7fffffff;
#pragma unroll
        for (int j = 0; j < 2; ++j) {
          int col = c0 + 32 * j;
          if (col < DD) {
            float x = acc[r][j] + sb[col];
            acc[r][j] = x;
            if (x > bv) { bv = x; bi = col; }
          }
        }
#pragma unroll
        for (int m = 16; m >= 1; m >>= 1) {
          float ov = __shfl_xor(bv, m);
          int   oi = __shfl_xor(bi, m);
          if (ov > bv || (ov == bv && oi < bi)) { bv = ov; bi = oi; }
        }
        float s = 0.f;
#pragma unroll
        for (int j = 0; j < 2; ++j) {
          int col = c0 + 32 * j;
          if (col < DD) s += __expf(acc[r][j] - bv);
        }
#pragma unroll
        for (int m = 16; m >= 1; m >>= 1) s += __shfl_xor(s, m);
        bvpl[r] = bv + __logf(s);
        if (c0 == 0) out[OFF4 + order[rowBase + rg + 8 * r]] = (float)bi;
      }

#pragma unroll 1
      for (int c = 0; c < 4; ++c) {
        __syncthreads();
#pragma unroll
        for (int j = 0; j < 2; ++j) {
          int col = c0 + 32 * j;
          if (col < DD) {
            float lg = acc[c][j];
            sU[rg * DD + col] = lg - bvpl[c];
            sU[416 + rg * DD + col] = lg;
          }
        }
        __syncthreads();
        int q0 = rowBase + 8 * c;
        f32x4* dC = (f32x4*)(out + OFF0 + (size_t)q0 * DD);
        f32x4* dL = (f32x4*)(out + OFF2 + (size_t)q0 * DD);
        for (int i = tid; i < 208; i += 256) {
          f32x4 v = ((f32x4*)sU)[i];
          if (i < 104) __builtin_nontemporal_store(v, dC + i);
          else         __builtin_nontemporal_store(v, dL + (i - 104));
        }
      }
    }
  }
}

extern "C" void kernel_launch(void* const* d_in, const int* in_sizes, int n_in,
                              void* d_out, int out_size, void* d_ws, size_t ws_size,
                              hipStream_t stream) {
  const float* h    = (const float*)d_in[0];
  const int*   nt   = (const int*)d_in[1];
  const float* FCw  = (const float*)d_in[2];
  const float* FCb  = (const float*)d_in[3];
  const float* Wpl  = (const float*)d_in[4];
  const float* Went = (const float*)d_in[5];
  float* out = (float*)d_out;

  int* order     = (int*)d_ws;                 // N
  int* partial   = order + NTOT;               // 384*3
  int* blockBase = partial + SORT_BLOCKS * 3;  // 384*3
  float* Wc  = (float*)(blockBase + SORT_BLOCKS * 3);  // 151*52 (16B-aligned)
  float* bc  = Wc + VE * DD;                   // 151 (+1 pad)
  float* Wpc = bc + VE + 1;                    // 52*52
  float* bpc = Wpc + DD * DD;                  // 52

  count_combine_kernel<<<SORT_BLOCKS + 43, 256, 0, stream>>>(nt, partial,
                                                             FCw, FCb, Wpl, Went,
                                                             Wc, bc, Wpc, bpc);
  scan_kernel   <<<1, SORT_BLOCKS, 0, stream>>>(partial, blockBase);
  scatter_kernel<<<SORT_BLOCKS, 256, 0, stream>>>(nt, blockBase, order);
  main_kernel   <<<768, 256, 0, stream>>>(h, order, Wc, bc, Wpc, bpc, out);
}

// Round 19
// 180.260 us; speedup vs baseline: 1.0223x; 1.0223x over previous
//
#include <hip/hip_runtime.h>
#include <float.h>

#define DD 52
#define VE 151
#define NTOT 393216
#define PSZ 131072

// output offsets (floats)
#define OFF0 0                       // predicate_conf  P*52
#define OFF1 (PSZ*DD)                // entity_conf     P*151
#define OFF2 (OFF1 + PSZ*VE)         // predicate_logits P*52
#define OFF3 (OFF2 + PSZ*DD)         // entity_logits   P*151
#define OFF4 (OFF3 + PSZ*VE)         // all_labels      N (as float)

#define SORT_BLOCKS 384              // N / 1024
#define TMR 32                       // rows per tile

typedef float f32x4 __attribute__((ext_vector_type(4)));

// ---------- count (blocks 0..383) + weight-fold (blocks 384..426) ----------
__global__ __launch_bounds__(256) void count_combine_kernel(const int* __restrict__ nt,
                                                            int* __restrict__ partial,
                                                            const float* __restrict__ FCw,
                                                            const float* __restrict__ FCb,
                                                            const float* __restrict__ Wpl,
                                                            const float* __restrict__ Went,
                                                            float* __restrict__ Wc,
                                                            float* __restrict__ bc,
                                                            float* __restrict__ Wpc,
                                                            float* __restrict__ bpc) {
  int tid = threadIdx.x;
  if (blockIdx.x < SORT_BLOCKS) {
    __shared__ int cnt[3];
    if (tid < 3) cnt[tid] = 0;
    __syncthreads();
    int base = blockIdx.x * 1024 + tid * 4;
    int4 v = *(const int4*)(nt + base);
    int t0 = min(max(v.x, 0), 2), t1 = min(max(v.y, 0), 2);
    int t2 = min(max(v.z, 0), 2), t3 = min(max(v.w, 0), 2);
    atomicAdd(&cnt[t0], 1); atomicAdd(&cnt[t1], 1);
    atomicAdd(&cnt[t2], 1); atomicAdd(&cnt[t3], 1);
    __syncthreads();
    if (tid < 3) partial[blockIdx.x * 3 + tid] = cnt[tid];
  } else {
    int idx = (blockIdx.x - SORT_BLOCKS) * 256 + tid;
    if (idx < VE * DD) {
      int v = idx / DD, k = idx % DD;
      float s = 0.f;
      for (int d = 0; d < DD; ++d) s = fmaf(Went[v * DD + d], FCw[d * DD + k], s);
      Wc[idx] = s;
    } else if (idx < VE * DD + VE) {
      int v = idx - VE * DD;
      float s = 0.f;
      for (int d = 0; d < DD; ++d) s = fmaf(FCb[d], Went[v * DD + d], s);
      bc[v] = s;
    } else if (idx < VE * DD + VE + DD * DD) {
      int t2 = idx - (VE * DD + VE);
      int j = t2 / DD, k = t2 % DD;
      float s = 0.f;
      for (int d = 0; d < DD; ++d) s = fmaf(FCw[d * DD + k], Wpl[d * DD + j], s);
      Wpc[t2] = s;
    } else if (idx < VE * DD + VE + DD * DD + DD) {
      int j = idx - (VE * DD + VE + DD * DD);
      float s = 0.f;
      for (int d = 0; d < DD; ++d) s = fmaf(FCb[d], Wpl[d * DD + j], s);
      bpc[j] = s;
    }
  }
}

__global__ __launch_bounds__(384) void scan_kernel(const int* __restrict__ partial,
                                                   int* __restrict__ blockBase) {
  __shared__ int sA[3][SORT_BLOCKS];
  int b = threadIdx.x;
  int p0 = partial[b * 3 + 0], p1 = partial[b * 3 + 1], p2 = partial[b * 3 + 2];
  sA[0][b] = p0; sA[1][b] = p1; sA[2][b] = p2;
  __syncthreads();
  for (int off = 1; off < SORT_BLOCKS; off <<= 1) {
    int a0 = 0, a1 = 0, a2 = 0;
    if (b >= off) { a0 = sA[0][b - off]; a1 = sA[1][b - off]; a2 = sA[2][b - off]; }
    __syncthreads();
    sA[0][b] += a0; sA[1][b] += a1; sA[2][b] += a2;
    __syncthreads();
  }
  int tot0 = sA[0][SORT_BLOCKS - 1];
  int tot1 = sA[1][SORT_BLOCKS - 1];
  blockBase[b * 3 + 0] = sA[0][b] - p0;
  blockBase[b * 3 + 1] = tot0 + sA[1][b] - p1;
  blockBase[b * 3 + 2] = tot0 + tot1 + sA[2][b] - p2;
}

__global__ __launch_bounds__(256) void scatter_kernel(const int* __restrict__ nt,
                                                      const int* __restrict__ blockBase,
                                                      int* __restrict__ order) {
  __shared__ int s0[256], s1[256], s2[256];
  int tid = threadIdx.x;
  int gbase = blockIdx.x * 1024 + tid * 4;
  int4 v = *(const int4*)(nt + gbase);
  int t[4] = { min(max(v.x, 0), 2), min(max(v.y, 0), 2),
               min(max(v.z, 0), 2), min(max(v.w, 0), 2) };
  int c0 = 0, c1 = 0, c2 = 0;
#pragma unroll
  for (int i = 0; i < 4; ++i) { c0 += (t[i] == 0); c1 += (t[i] == 1); c2 += (t[i] == 2); }
  s0[tid] = c0; s1[tid] = c1; s2[tid] = c2;
  __syncthreads();
  for (int off = 1; off < 256; off <<= 1) {
    int a0 = 0, a1 = 0, a2 = 0;
    if (tid >= off) { a0 = s0[tid - off]; a1 = s1[tid - off]; a2 = s2[tid - off]; }
    __syncthreads();
    s0[tid] += a0; s1[tid] += a1; s2[tid] += a2;
    __syncthreads();
  }
  int o0 = blockBase[blockIdx.x * 3 + 0] + s0[tid] - c0;
  int o1 = blockBase[blockIdx.x * 3 + 1] + s1[tid] - c1;
  int o2 = blockBase[blockIdx.x * 3 + 2] + s2[tid] - c2;
#pragma unroll
  for (int i = 0; i < 4; ++i) {
    int ty = t[i]; int dest;
    if (ty == 0) dest = o0++;
    else if (ty == 1) dest = o1++;
    else dest = o2++;
    order[dest] = gbase + i;
  }
}

// ---------- fused main kernel (byte-exact R17 — session optimum) ----------
// grid = 768 (3 blocks/CU). bid<512: ent/blank block, 16 tiles of 32 rows,
// interleaved ent/blank. bid in [512,768): pred block, 16 tiles of 32 rows.
// Epilogue: 8-row chunks (R16 win, −8 barriers/tile), both surfaces staged
// in LDS, one clean f32x4-from-LDS NT store per thread per iteration.
// INVARIANTS (session-measured, do not violate):
//  - h staged via LDS with sOrd in LDS (R10: direct-global h = +75%;
//    R18: direct-global order = +5%)
//  - epilogue: both surfaces staged in LDS, clean f32x4 NT store/thread/iter
//    (R5-R8: any deviation -> 4-16x HBM write amplification)
//  - 32-row tiles, acc[4][5] (R13/R14: acc[8][5] -> scratch spill, 3-10x)
//  - no runtime indexing of per-thread arrays beyond acc[c] patterns already
//    proven in the shipped binary
__global__ __launch_bounds__(256, 3) void main_kernel(const float* __restrict__ h,
                                                      const int* __restrict__ order,
                                                      const float* __restrict__ Wc,
                                                      const float* __restrict__ bc,
                                                      const float* __restrict__ Wpc,
                                                      const float* __restrict__ bpc,
                                                      float* __restrict__ out) {
  __shared__ float sW[VE * DD];   // 31408 B (pred uses 52*52)
  __shared__ float sU[2416];      // 9664 B: h-tile (416 f4) / chunk buf (604 f4)
  __shared__ float sb[VE + 1];
  __shared__ int   sOrd[TMR];
  int tid = threadIdx.x, bid = blockIdx.x;
  int rg = tid >> 5, c0 = tid & 31;

  if (bid < 512) {
    // ---------- entity / blank ----------
    for (int i = tid; i < VE * 13; i += 256) ((float4*)sW)[i] = ((const float4*)Wc)[i];
    if (tid < VE) sb[tid] = bc[tid];
    int e = bid;

    int wbase[5];
#pragma unroll
    for (int j = 0; j < 5; ++j) {
      int col = c0 + 32 * j; if (col >= VE) col = 0;
      wbase[j] = col * 13;
    }
    int hbase[4];
#pragma unroll
    for (int r = 0; r < 4; ++r) hbase[r] = (rg + 8 * r) * 13;

#pragma unroll 1
    for (int tt = 0; tt < 16; ++tt) {
      bool isEnt = !(tt & 1);
      int idx = tt >> 1;
      int rowBase = (isEnt ? PSZ : 2 * PSZ) + e * 256 + idx * 32;

      __syncthreads();
      if (tid < TMR) sOrd[tid] = order[rowBase + tid];
      __syncthreads();
      for (int i = tid; i < TMR * 13; i += 256) {
        int row = i / 13, f = i % 13;
        ((float4*)sU)[i] = ((const float4*)(h + (size_t)sOrd[row] * DD))[f];
      }
      __syncthreads();

      float acc[4][5];
#pragma unroll
      for (int r = 0; r < 4; ++r)
#pragma unroll
        for (int j = 0; j < 5; ++j) acc[r][j] = 0.f;

#pragma unroll
      for (int kc = 0; kc < 13; ++kc) {
        float4 wv[5];
#pragma unroll
        for (int j = 0; j < 5; ++j)
          wv[j] = ((const float4*)sW)[wbase[j] + kc];
#pragma unroll
        for (int r = 0; r < 4; ++r) {
          float4 hv = ((float4*)sU)[hbase[r] + kc];
#pragma unroll
          for (int j = 0; j < 5; ++j) {
            acc[r][j] = fmaf(hv.x, wv[j].x, acc[r][j]);
            acc[r][j] = fmaf(hv.y, wv[j].y, acc[r][j]);
            acc[r][j] = fmaf(hv.z, wv[j].z, acc[r][j]);
            acc[r][j] = fmaf(hv.w, wv[j].w, acc[r][j]);
          }
        }
      }

      float bvpl[4];
#pragma unroll 1
      for (int r = 0; r < 4; ++r) {
        float bv = -FLT_MAX; int bi = 0x7fffffff;
#pragma unroll
        for (int j = 0; j < 5; ++j) {
          int col = c0 + 32 * j;
          if (col < VE) {
            float x = acc[r][j] + sb[col];
            acc[r][j] = x;
            if (x > bv) { bv = x; bi = col; }
          }
        }
#pragma unroll
        for (int m = 16; m >= 1; m >>= 1) {
          float ov = __shfl_xor(bv, m);
          int   oi = __shfl_xor(bi, m);
          if (ov > bv || (ov == bv && oi < bi)) { bv = ov; bi = oi; }
        }
        if (isEnt) {
          float s = 0.f;
#pragma unroll
          for (int j = 0; j < 5; ++j) {
            int col = c0 + 32 * j;
            if (col < VE) s += __expf(acc[r][j] - bv);
          }
#pragma unroll
          for (int m = 16; m >= 1; m >>= 1) s += __shfl_xor(s, m);
          bvpl[r] = bv + __logf(s);
        }
        if (c0 == 0) out[OFF4 + sOrd[rg + 8 * r]] = (float)bi;
      }

      if (isEnt) {
        int q0base = rowBase - PSZ;
#pragma unroll 1
        for (int c = 0; c < 4; ++c) {
          __syncthreads();
#pragma unroll
          for (int j = 0; j < 5; ++j) {
            int col = c0 + 32 * j;
            if (col < VE) {
              float lg = acc[c][j];
              sU[rg * VE + col] = lg - bvpl[c];
              sU[1208 + rg * VE + col] = lg;
            }
          }
          __syncthreads();
          int q0 = q0base + 8 * c;
          f32x4* dC = (f32x4*)(out + OFF1 + (size_t)q0 * VE);
          f32x4* dL = (f32x4*)(out + OFF3 + (size_t)q0 * VE);
          for (int i = tid; i < 604; i += 256) {
            f32x4 v = ((f32x4*)sU)[i];
            if (i < 302) __builtin_nontemporal_store(v, dC + i);
            else         __builtin_nontemporal_store(v, dL + (i - 302));
          }
        }
      }
    }
  } else {
    // ---------- predicate : 256 blocks x 16 tiles ----------
    for (int i = tid; i < DD * 13; i += 256) ((float4*)sW)[i] = ((const float4*)Wpc)[i];
    if (tid < DD) sb[tid] = bpc[tid];
    int p = bid - 512;

    int wbase[2];
#pragma unroll
    for (int j = 0; j < 2; ++j) {
      int col = c0 + 32 * j; if (col >= DD) col = 0;
      wbase[j] = col * 13;
    }
    int hbase[4];
#pragma unroll
    for (int r = 0; r < 4; ++r) hbase[r] = (rg + 8 * r) * 13;

#pragma unroll 1
    for (int tt = 0; tt < 16; ++tt) {
      int rowBase = p * 512 + tt * 32;

      __syncthreads();
      if (tid < TMR) sOrd[tid] = order[rowBase + tid];
      __syncthreads();
      for (int i = tid; i < TMR * 13; i += 256) {
        int row = i / 13, f = i % 13;
        ((float4*)sU)[i] = ((const float4*)(h + (size_t)sOrd[row] * DD))[f];
      }
      __syncthreads();

      float acc[4][2];
#pragma unroll
      for (int r = 0; r < 4; ++r) { acc[r][0] = 0.f; acc[r][1] = 0.f; }

#pragma unroll
      for (int kc = 0; kc < 13; ++kc) {
        float4 wv[2];
#pragma unroll
        for (int j = 0; j < 2; ++j)
          wv[j] = ((const float4*)sW)[wbase[j] + kc];
#pragma unroll
        for (int r = 0; r < 4; ++r) {
          float4 hv = ((float4*)sU)[hbase[r] + kc];
#pragma unroll
          for (int j = 0; j < 2; ++j) {
            acc[r][j] = fmaf(hv.x, wv[j].x, acc[r][j]);
            acc[r][j] = fmaf(hv.y, wv[j].y, acc[r][j]);
            acc[r][j] = fmaf(hv.z, wv[j].z, acc[r][j]);
            acc[r][j] = fmaf(hv.w, wv[j].w, acc[r][j]);
          }
        }
      }

      float bvpl[4];
#pragma unroll 1
      for (int r = 0; r < 4; ++r) {
        float bv = -FLT_MAX; int bi = 0x7fffffff;
#pragma unroll
        for (int j = 0; j < 2; ++j) {
          int col = c0 + 32 * j;
          if (col < DD) {
            float x = acc[r][j] + sb[col];
            acc[r][j] = x;
            if (x > bv) { bv = x; bi = col; }
          }
        }
#pragma unroll
        for (int m = 16; m >= 1; m >>= 1) {
          float ov = __shfl_xor(bv, m);
          int   oi = __shfl_xor(bi, m);
          if (ov > bv || (ov == bv && oi < bi)) { bv = ov; bi = oi; }
        }
        float s = 0.f;
#pragma unroll
        for (int j = 0; j < 2; ++j) {
          int col = c0 + 32 * j;
          if (col < DD) s += __expf(acc[r][j] - bv);
        }
#pragma unroll
        for (int m = 16; m >= 1; m >>= 1) s += __shfl_xor(s, m);
        bvpl[r] = bv + __logf(s);
        if (c0 == 0) out[OFF4 + sOrd[rg + 8 * r]] = (float)bi;
      }

#pragma unroll 1
      for (int c = 0; c < 4; ++c) {
        __syncthreads();
#pragma unroll
        for (int j = 0; j < 2; ++j) {
          int col = c0 + 32 * j;
          if (col < DD) {
            float lg = acc[c][j];
            sU[rg * DD + col] = lg - bvpl[c];
            sU[416 + rg * DD + col] = lg;
          }
        }
        __syncthreads();
        int q0 = rowBase + 8 * c;
        f32x4* dC = (f32x4*)(out + OFF0 + (size_t)q0 * DD);
        f32x4* dL = (f32x4*)(out + OFF2 + (size_t)q0 * DD);
        for (int i = tid; i < 208; i += 256) {
          f32x4 v = ((f32x4*)sU)[i];
          if (i < 104) __builtin_nontemporal_store(v, dC + i);
          else         __builtin_nontemporal_store(v, dL + (i - 104));
        }
      }
    }
  }
}

extern "C" void kernel_launch(void* const* d_in, const int* in_sizes, int n_in,
                              void* d_out, int out_size, void* d_ws, size_t ws_size,
                              hipStream_t stream) {
  const float* h    = (const float*)d_in[0];
  const int*   nt   = (const int*)d_in[1];
  const float* FCw  = (const float*)d_in[2];
  const float* FCb  = (const float*)d_in[3];
  const float* Wpl  = (const float*)d_in[4];
  const float* Went = (const float*)d_in[5];
  float* out = (float*)d_out;

  int* order     = (int*)d_ws;                 // N
  int* partial   = order + NTOT;               // 384*3
  int* blockBase = partial + SORT_BLOCKS * 3;  // 384*3
  float* Wc  = (float*)(blockBase + SORT_BLOCKS * 3);  // 151*52 (16B-aligned)
  float* bc  = Wc + VE * DD;                   // 151 (+1 pad)
  float* Wpc = bc + VE + 1;                    // 52*52
  float* bpc = Wpc + DD * DD;                  // 52

  count_combine_kernel<<<SORT_BLOCKS + 43, 256, 0, stream>>>(nt, partial,
                                                             FCw, FCb, Wpl, Went,
                                                             Wc, bc, Wpc, bpc);
  scan_kernel   <<<1, SORT_BLOCKS, 0, stream>>>(partial, blockBase);
  scatter_kernel<<<SORT_BLOCKS, 256, 0, stream>>>(nt, blockBase, order);
  main_kernel   <<<768, 256, 0, stream>>>(h, order, Wc, bc, Wpc, bpc, out);
}

// Round 20
// 178.655 us; speedup vs baseline: 1.0315x; 1.0090x over previous
//
#include <hip/hip_runtime.h>
#include <float.h>

#define DD 52
#define VE 151
#define NTOT 393216
#define PSZ 131072

// output offsets (floats)
#define OFF0 0                       // predicate_conf  P*52
#define OFF1 (PSZ*DD)                // entity_conf     P*151
#define OFF2 (OFF1 + PSZ*VE)         // predicate_logits P*52
#define OFF3 (OFF2 + PSZ*DD)         // entity_logits   P*151
#define OFF4 (OFF3 + PSZ*VE)         // all_labels      N (as float)

#define SORT_BLOCKS 384              // N / 1024
#define TMR 32                       // rows per tile

typedef float f32x4 __attribute__((ext_vector_type(4)));

// ---------- count (blocks 0..383) + weight-fold (blocks 384..426) ----------
__global__ __launch_bounds__(256) void count_combine_kernel(const int* __restrict__ nt,
                                                            int* __restrict__ partial,
                                                            const float* __restrict__ FCw,
                                                            const float* __restrict__ FCb,
                                                            const float* __restrict__ Wpl,
                                                            const float* __restrict__ Went,
                                                            float* __restrict__ Wc,
                                                            float* __restrict__ bc,
                                                            float* __restrict__ Wpc,
                                                            float* __restrict__ bpc) {
  int tid = threadIdx.x;
  if (blockIdx.x < SORT_BLOCKS) {
    __shared__ int cnt[3];
    if (tid < 3) cnt[tid] = 0;
    __syncthreads();
    int base = blockIdx.x * 1024 + tid * 4;
    int4 v = *(const int4*)(nt + base);
    int t0 = min(max(v.x, 0), 2), t1 = min(max(v.y, 0), 2);
    int t2 = min(max(v.z, 0), 2), t3 = min(max(v.w, 0), 2);
    atomicAdd(&cnt[t0], 1); atomicAdd(&cnt[t1], 1);
    atomicAdd(&cnt[t2], 1); atomicAdd(&cnt[t3], 1);
    __syncthreads();
    if (tid < 3) partial[blockIdx.x * 3 + tid] = cnt[tid];
  } else {
    int idx = (blockIdx.x - SORT_BLOCKS) * 256 + tid;
    if (idx < VE * DD) {
      int v = idx / DD, k = idx % DD;
      float s = 0.f;
      for (int d = 0; d < DD; ++d) s = fmaf(Went[v * DD + d], FCw[d * DD + k], s);
      Wc[idx] = s;
    } else if (idx < VE * DD + VE) {
      int v = idx - VE * DD;
      float s = 0.f;
      for (int d = 0; d < DD; ++d) s = fmaf(FCb[d], Went[v * DD + d], s);
      bc[v] = s;
    } else if (idx < VE * DD + VE + DD * DD) {
      int t2 = idx - (VE * DD + VE);
      int j = t2 / DD, k = t2 % DD;
      float s = 0.f;
      for (int d = 0; d < DD; ++d) s = fmaf(FCw[d * DD + k], Wpl[d * DD + j], s);
      Wpc[t2] = s;
    } else if (idx < VE * DD + VE + DD * DD + DD) {
      int j = idx - (VE * DD + VE + DD * DD);
      float s = 0.f;
      for (int d = 0; d < DD; ++d) s = fmaf(FCb[d], Wpl[d * DD + j], s);
      bpc[j] = s;
    }
  }
}

__global__ __launch_bounds__(384) void scan_kernel(const int* __restrict__ partial,
                                                   int* __restrict__ blockBase) {
  __shared__ int sA[3][SORT_BLOCKS];
  int b = threadIdx.x;
  int p0 = partial[b * 3 + 0], p1 = partial[b * 3 + 1], p2 = partial[b * 3 + 2];
  sA[0][b] = p0; sA[1][b] = p1; sA[2][b] = p2;
  __syncthreads();
  for (int off = 1; off < SORT_BLOCKS; off <<= 1) {
    int a0 = 0, a1 = 0, a2 = 0;
    if (b >= off) { a0 = sA[0][b - off]; a1 = sA[1][b - off]; a2 = sA[2][b - off]; }
    __syncthreads();
    sA[0][b] += a0; sA[1][b] += a1; sA[2][b] += a2;
    __syncthreads();
  }
  int tot0 = sA[0][SORT_BLOCKS - 1];
  int tot1 = sA[1][SORT_BLOCKS - 1];
  blockBase[b * 3 + 0] = sA[0][b] - p0;
  blockBase[b * 3 + 1] = tot0 + sA[1][b] - p1;
  blockBase[b * 3 + 2] = tot0 + tot1 + sA[2][b] - p2;
}

__global__ __launch_bounds__(256) void scatter_kernel(const int* __restrict__ nt,
                                                      const int* __restrict__ blockBase,
                                                      int* __restrict__ order) {
  __shared__ int s0[256], s1[256], s2[256];
  int tid = threadIdx.x;
  int gbase = blockIdx.x * 1024 + tid * 4;
  int4 v = *(const int4*)(nt + gbase);
  int t[4] = { min(max(v.x, 0), 2), min(max(v.y, 0), 2),
               min(max(v.z, 0), 2), min(max(v.w, 0), 2) };
  int c0 = 0, c1 = 0, c2 = 0;
#pragma unroll
  for (int i = 0; i < 4; ++i) { c0 += (t[i] == 0); c1 += (t[i] == 1); c2 += (t[i] == 2); }
  s0[tid] = c0; s1[tid] = c1; s2[tid] = c2;
  __syncthreads();
  for (int off = 1; off < 256; off <<= 1) {
    int a0 = 0, a1 = 0, a2 = 0;
    if (tid >= off) { a0 = s0[tid - off]; a1 = s1[tid - off]; a2 = s2[tid - off]; }
    __syncthreads();
    s0[tid] += a0; s1[tid] += a1; s2[tid] += a2;
    __syncthreads();
  }
  int o0 = blockBase[blockIdx.x * 3 + 0] + s0[tid] - c0;
  int o1 = blockBase[blockIdx.x * 3 + 1] + s1[tid] - c1;
  int o2 = blockBase[blockIdx.x * 3 + 2] + s2[tid] - c2;
#pragma unroll
  for (int i = 0; i < 4; ++i) {
    int ty = t[i]; int dest;
    if (ty == 0) dest = o0++;
    else if (ty == 1) dest = o1++;
    else dest = o2++;
    order[dest] = gbase + i;
  }
}

// ---------- fused main kernel ----------
// Base = R17 (session optimum). R20 single variable: epilogue chunk
// DOUBLE-BUFFER — one barrier per chunk instead of two. Sequence per tile:
// bar(h-safe); W0->bufA; loop c=0..3 { bar; W(c+1)->other buf; R(c)+NT }.
// 5 epilogue barriers/tile vs 8; chunk-writes overlap global NT stores.
// sU = 2 x 2416 floats (ent chunk = 1208 conf + 1208 logits). LDS 51.5 KB
// -> still 3 blocks/CU. Store loop keeps the sacred shape exactly.
// INVARIANTS (session-measured, do not violate):
//  - h staged via LDS with sOrd in LDS (R10/R18)
//  - epilogue: both surfaces staged in LDS, clean f32x4 NT store/thread/iter
//    (R5-R8: any deviation -> 4-16x HBM write amplification)
//  - 32-row tiles, acc[4][5] (R13/R14: acc[8][5] -> scratch spill)
__global__ __launch_bounds__(256, 3) void main_kernel(const float* __restrict__ h,
                                                      const int* __restrict__ order,
                                                      const float* __restrict__ Wc,
                                                      const float* __restrict__ bc,
                                                      const float* __restrict__ Wpc,
                                                      const float* __restrict__ bpc,
                                                      float* __restrict__ out) {
  __shared__ float sW[VE * DD];   // 31408 B (pred uses 52*52)
  __shared__ float sU[4832];      // 19328 B: h-tile (416 f4) / 2x chunk buf
  __shared__ float sb[VE + 1];
  __shared__ int   sOrd[TMR];
  int tid = threadIdx.x, bid = blockIdx.x;
  int rg = tid >> 5, c0 = tid & 31;

  if (bid < 512) {
    // ---------- entity / blank ----------
    for (int i = tid; i < VE * 13; i += 256) ((float4*)sW)[i] = ((const float4*)Wc)[i];
    if (tid < VE) sb[tid] = bc[tid];
    int e = bid;

    int wbase[5];
#pragma unroll
    for (int j = 0; j < 5; ++j) {
      int col = c0 + 32 * j; if (col >= VE) col = 0;
      wbase[j] = col * 13;
    }
    int hbase[4];
#pragma unroll
    for (int r = 0; r < 4; ++r) hbase[r] = (rg + 8 * r) * 13;

#pragma unroll 1
    for (int tt = 0; tt < 16; ++tt) {
      bool isEnt = !(tt & 1);
      int idx = tt >> 1;
      int rowBase = (isEnt ? PSZ : 2 * PSZ) + e * 256 + idx * 32;

      __syncthreads();
      if (tid < TMR) sOrd[tid] = order[rowBase + tid];
      __syncthreads();
      for (int i = tid; i < TMR * 13; i += 256) {
        int row = i / 13, f = i % 13;
        ((float4*)sU)[i] = ((const float4*)(h + (size_t)sOrd[row] * DD))[f];
      }
      __syncthreads();

      float acc[4][5];
#pragma unroll
      for (int r = 0; r < 4; ++r)
#pragma unroll
        for (int j = 0; j < 5; ++j) acc[r][j] = 0.f;

#pragma unroll
      for (int kc = 0; kc < 13; ++kc) {
        float4 wv[5];
#pragma unroll
        for (int j = 0; j < 5; ++j)
          wv[j] = ((const float4*)sW)[wbase[j] + kc];
#pragma unroll
        for (int r = 0; r < 4; ++r) {
          float4 hv = ((float4*)sU)[hbase[r] + kc];
#pragma unroll
          for (int j = 0; j < 5; ++j) {
            acc[r][j] = fmaf(hv.x, wv[j].x, acc[r][j]);
            acc[r][j] = fmaf(hv.y, wv[j].y, acc[r][j]);
            acc[r][j] = fmaf(hv.z, wv[j].z, acc[r][j]);
            acc[r][j] = fmaf(hv.w, wv[j].w, acc[r][j]);
          }
        }
      }

      float bvpl[4];
#pragma unroll 1
      for (int r = 0; r < 4; ++r) {
        float bv = -FLT_MAX; int bi = 0x7fffffff;
#pragma unroll
        for (int j = 0; j < 5; ++j) {
          int col = c0 + 32 * j;
          if (col < VE) {
            float x = acc[r][j] + sb[col];
            acc[r][j] = x;
            if (x > bv) { bv = x; bi = col; }
          }
        }
#pragma unroll
        for (int m = 16; m >= 1; m >>= 1) {
          float ov = __shfl_xor(bv, m);
          int   oi = __shfl_xor(bi, m);
          if (ov > bv || (ov == bv && oi < bi)) { bv = ov; bi = oi; }
        }
        if (isEnt) {
          float s = 0.f;
#pragma unroll
          for (int j = 0; j < 5; ++j) {
            int col = c0 + 32 * j;
            if (col < VE) s += __expf(acc[r][j] - bv);
          }
#pragma unroll
          for (int m = 16; m >= 1; m >>= 1) s += __shfl_xor(s, m);
          bvpl[r] = bv + __logf(s);
        }
        if (c0 == 0) out[OFF4 + sOrd[rg + 8 * r]] = (float)bi;
      }

      if (isEnt) {
        int q0base = rowBase - PSZ;
        __syncthreads();               // h-tile reads complete; bufA free
#pragma unroll
        for (int j = 0; j < 5; ++j) {  // write chunk 0 -> buffer A
          int col = c0 + 32 * j;
          if (col < VE) {
            float lg = acc[0][j];
            sU[rg * VE + col] = lg - bvpl[0];
            sU[1208 + rg * VE + col] = lg;
          }
        }
#pragma unroll 1
        for (int c = 0; c < 4; ++c) {
          __syncthreads();             // chunk c visible; chunk c-1 reads done
          float* bufc = sU + (c & 1) * 2416;
          if (c < 3) {
            float* bufn = sU + ((c + 1) & 1) * 2416;
            int cn = c + 1;
#pragma unroll
            for (int j = 0; j < 5; ++j) {
              int col = c0 + 32 * j;
              if (col < VE) {
                float lg = acc[cn][j];
                bufn[rg * VE + col] = lg - bvpl[cn];
                bufn[1208 + rg * VE + col] = lg;
              }
            }
          }
          int q0 = q0base + 8 * c;
          f32x4* dC = (f32x4*)(out + OFF1 + (size_t)q0 * VE);
          f32x4* dL = (f32x4*)(out + OFF3 + (size_t)q0 * VE);
          f32x4* bf = (f32x4*)bufc;
          for (int i = tid; i < 604; i += 256) {
            f32x4 v = bf[i];
            if (i < 302) __builtin_nontemporal_store(v, dC + i);
            else         __builtin_nontemporal_store(v, dL + (i - 302));
          }
        }
      }
    }
  } else {
    // ---------- predicate : 256 blocks x 16 tiles ----------
    for (int i = tid; i < DD * 13; i += 256) ((float4*)sW)[i] = ((const float4*)Wpc)[i];
    if (tid < DD) sb[tid] = bpc[tid];
    int p = bid - 512;

    int wbase[2];
#pragma unroll
    for (int j = 0; j < 2; ++j) {
      int col = c0 + 32 * j; if (col >= DD) col = 0;
      wbase[j] = col * 13;
    }
    int hbase[4];
#pragma unroll
    for (int r = 0; r < 4; ++r) hbase[r] = (rg + 8 * r) * 13;

#pragma unroll 1
    for (int tt = 0; tt < 16; ++tt) {
      int rowBase = p * 512 + tt * 32;

      __syncthreads();
      if (tid < TMR) sOrd[tid] = order[rowBase + tid];
      __syncthreads();
      for (int i = tid; i < TMR * 13; i += 256) {
        int row = i / 13, f = i % 13;
        ((float4*)sU)[i] = ((const float4*)(h + (size_t)sOrd[row] * DD))[f];
      }
      __syncthreads();

      float acc[4][2];
#pragma unroll
      for (int r = 0; r < 4; ++r) { acc[r][0] = 0.f; acc[r][1] = 0.f; }

#pragma unroll
      for (int kc = 0; kc < 13; ++kc) {
        float4 wv[2];
#pragma unroll
        for (int j = 0; j < 2; ++j)
          wv[j] = ((const float4*)sW)[wbase[j] + kc];
#pragma unroll
        for (int r = 0; r < 4; ++r) {
          float4 hv = ((float4*)sU)[hbase[r] + kc];
#pragma unroll
          for (int j = 0; j < 2; ++j) {
            acc[r][j] = fmaf(hv.x, wv[j].x, acc[r][j]);
            acc[r][j] = fmaf(hv.y, wv[j].y, acc[r][j]);
            acc[r][j] = fmaf(hv.z, wv[j].z, acc[r][j]);
            acc[r][j] = fmaf(hv.w, wv[j].w, acc[r][j]);
          }
        }
      }

      float bvpl[4];
#pragma unroll 1
      for (int r = 0; r < 4; ++r) {
        float bv = -FLT_MAX; int bi = 0x7fffffff;
#pragma unroll
        for (int j = 0; j < 2; ++j) {
          int col = c0 + 32 * j;
          if (col < DD) {
            float x = acc[r][j] + sb[col];
            acc[r][j] = x;
            if (x > bv) { bv = x; bi = col; }
          }
        }
#pragma unroll
        for (int m = 16; m >= 1; m >>= 1) {
          float ov = __shfl_xor(bv, m);
          int   oi = __shfl_xor(bi, m);
          if (ov > bv || (ov == bv && oi < bi)) { bv = ov; bi = oi; }
        }
        float s = 0.f;
#pragma unroll
        for (int j = 0; j < 2; ++j) {
          int col = c0 + 32 * j;
          if (col < DD) s += __expf(acc[r][j] - bv);
        }
#pragma unroll
        for (int m = 16; m >= 1; m >>= 1) s += __shfl_xor(s, m);
        bvpl[r] = bv + __logf(s);
        if (c0 == 0) out[OFF4 + sOrd[rg + 8 * r]] = (float)bi;
      }

      {
        __syncthreads();               // h-tile reads complete; bufA free
#pragma unroll
        for (int j = 0; j < 2; ++j) {  // write chunk 0 -> buffer A
          int col = c0 + 32 * j;
          if (col < DD) {
            float lg = acc[0][j];
            sU[rg * DD + col] = lg - bvpl[0];
            sU[416 + rg * DD + col] = lg;
          }
        }
#pragma unroll 1
        for (int c = 0; c < 4; ++c) {
          __syncthreads();
          float* bufc = sU + (c & 1) * 832;
          if (c < 3) {
            float* bufn = sU + ((c + 1) & 1) * 832;
            int cn = c + 1;
#pragma unroll
            for (int j = 0; j < 2; ++j) {
              int col = c0 + 32 * j;
              if (col < DD) {
                float lg = acc[cn][j];
                bufn[rg * DD + col] = lg - bvpl[cn];
                bufn[416 + rg * DD + col] = lg;
              }
            }
          }
          int q0 = rowBase + 8 * c;
          f32x4* dC = (f32x4*)(out + OFF0 + (size_t)q0 * DD);
          f32x4* dL = (f32x4*)(out + OFF2 + (size_t)q0 * DD);
          f32x4* bf = (f32x4*)bufc;
          for (int i = tid; i < 208; i += 256) {
            f32x4 v = bf[i];
            if (i < 104) __builtin_nontemporal_store(v, dC + i);
            else         __builtin_nontemporal_store(v, dL + (i - 104));
          }
        }
      }
    }
  }
}

extern "C" void kernel_launch(void* const* d_in, const int* in_sizes, int n_in,
                              void* d_out, int out_size, void* d_ws, size_t ws_size,
                              hipStream_t stream) {
  const float* h    = (const float*)d_in[0];
  const int*   nt   = (const int*)d_in[1];
  const float* FCw  = (const float*)d_in[2];
  const float* FCb  = (const float*)d_in[3];
  const float* Wpl  = (const float*)d_in[4];
  const float* Went = (const float*)d_in[5];
  float* out = (float*)d_out;

  int* order     = (int*)d_ws;                 // N
  int* partial   = order + NTOT;               // 384*3
  int* blockBase = partial + SORT_BLOCKS * 3;  // 384*3
  float* Wc  = (float*)(blockBase + SORT_BLOCKS * 3);  // 151*52 (16B-aligned)
  float* bc  = Wc + VE * DD;                   // 151 (+1 pad)
  float* Wpc = bc + VE + 1;                    // 52*52
  float* bpc = Wpc + DD * DD;                  // 52

  count_combine_kernel<<<SORT_BLOCKS + 43, 256, 0, stream>>>(nt, partial,
                                                             FCw, FCb, Wpl, Went,
                                                             Wc, bc, Wpc, bpc);
  scan_kernel   <<<1, SORT_BLOCKS, 0, stream>>>(partial, blockBase);
  scatter_kernel<<<SORT_BLOCKS, 256, 0, stream>>>(nt, blockBase, order);
  main_kernel   <<<768, 256, 0, stream>>>(h, order, Wc, bc, Wpc, bpc, out);
}